// Round 14
// baseline (203.597 us; speedup 1.0000x reference)
//
#include <hip/hip_runtime.h>
#include <math.h>

typedef unsigned short u16;
typedef __attribute__((ext_vector_type(8))) short short8;
typedef __attribute__((ext_vector_type(4))) short short4v;
typedef __attribute__((ext_vector_type(4))) float floatx4;
typedef __attribute__((ext_vector_type(2))) float f2;

#define BB 4
#define NN 1024
#define CC 512
#define HH 8
#define INNERD 512
#define BHCNT 32
#define MTOK 4096
#define NSPLIT 2

// ---- workspace layout (bytes) ----
constexpr size_t OFF_XB  = 0;                          // bf16 [4096][512]   = 4194304
constexpr size_t OFF_WQB = 4194304;                    // bf16 [1536][512]   = 1572864
constexpr size_t OFF_WPB = 5767168;                    // bf16 [512][512]    = 524288
constexpr size_t OFF_WEB = 6291456;                    // bf16 [64][64]      = 8192
constexpr size_t OFF_WSB = 6299648;                    // bf16 [64][64]      = 8192
constexpr size_t OFF_WHB = 6307840;                    // bf16 [32][64]      = 4096
constexpr size_t OFF_QKV = 6311936;                    // bf16 [3][B][H][N][64] = 12582912
constexpr size_t OFF_EQ  = 18894848;                   // bf16 [BH][N][64]   = 4194304
constexpr size_t OFF_EK  = 23089152;
constexpr size_t OFF_SQ  = 27283456;
constexpr size_t OFF_SK  = 31477760;
constexpr size_t OFF_HQ  = 35672064;                   // bf16 [BH][N][32]   = 2097152
constexpr size_t OFF_HK  = 37769216;
constexpr size_t OFF_VT  = 39866368;                   // bf16 [BH][64][N]   = 4194304
constexpr size_t OFF_EQN = 44060672;                   // fp32 [BH][N]       = 131072
constexpr size_t OFF_EKN = 44191744;
constexpr size_t OFF_HQN = 44322816;
constexpr size_t OFF_HKN = 44453888;
constexpr size_t OFF_AO  = 44584960;                   // bf16 [B][N][512]   = 4194304
constexpr size_t OFF_OP  = 48779264;                   // fp32 [2][BH][N][64]= 16777216
constexpr size_t OFF_LP  = 65556480;                   // fp32 [2][BH][N]    = 262144

// ---- fast native transcendentals (compile-safe fallbacks) ----
#if __has_builtin(__builtin_amdgcn_exp2f)
#define FEXP2(x) __builtin_amdgcn_exp2f(x)
#else
#define FEXP2(x) exp2f(x)
#endif
#if __has_builtin(__builtin_amdgcn_logf)
#define FLOG2(x) __builtin_amdgcn_logf(x)
#else
#define FLOG2(x) log2f(x)
#endif
#if __has_builtin(__builtin_amdgcn_sqrtf)
#define FSQRT(x) __builtin_amdgcn_sqrtf(x)
#else
#define FSQRT(x) sqrtf(x)
#endif
#if __has_builtin(__builtin_amdgcn_rcpf)
#define FRCP(x) __builtin_amdgcn_rcpf(x)
#else
#define FRCP(x) (1.0f / (x))
#endif

#define EFMA(a,b,c) __builtin_elementwise_fma(a,b,c)
#define EMAX(a,b)   __builtin_elementwise_max(a,b)
#define EMIN(a,b)   __builtin_elementwise_min(a,b)
#define EABS(a)     __builtin_elementwise_abs(a)

__device__ __forceinline__ short f2bf(float f) {
    unsigned u = __float_as_uint(f);
    unsigned r = u + 0x7fffu + ((u >> 16) & 1u);
    return (short)(r >> 16);
}
__device__ __forceinline__ floatx4 mfma16(short8 a, short8 b, floatx4 c) {
    return __builtin_amdgcn_mfma_f32_16x16x32_bf16(a, b, c, 0, 0, 0);
}
__device__ __forceinline__ float softplusf(float x) { return log1pf(expf(x)); }
__device__ __forceinline__ float qsum16(float v) {
    v += __shfl_xor(v, 1); v += __shfl_xor(v, 2);
    v += __shfl_xor(v, 4); v += __shfl_xor(v, 8);
    return v;
}
// fast tanh: (t-1)/(t+1), t = exp2(2x*log2e). bf16-rounded after.
__device__ __forceinline__ float ftanh(float x) {
    const float t = FEXP2(x * 2.8853900817779268f);
    return (t - 1.0f) * FRCP(t + 1.0f);
}

// ============================================================================
// K0: fp32 -> bf16 conversion of x / w_qkv / w_proj / w_e / w_s / w_h.
// ============================================================================
__global__ __launch_bounds__(256) void k0_cvt(
    const float* __restrict__ x, const float* __restrict__ wq,
    const float* __restrict__ wp, const float* __restrict__ we,
    const float* __restrict__ wsp, const float* __restrict__ whp,
    u16* __restrict__ xb, u16* __restrict__ wqb, u16* __restrict__ wpb,
    u16* __restrict__ web, u16* __restrict__ wsb, u16* __restrict__ whb) {
    const size_t i = ((size_t)blockIdx.x * 256 + threadIdx.x) * 4;
    const float* s; u16* d; size_t off;
    if (i < 2097152)      { s = x;   d = xb;  off = i; }
    else if (i < 2883584) { s = wq;  d = wqb; off = i - 2097152; }
    else if (i < 3145728) { s = wp;  d = wpb; off = i - 2883584; }
    else if (i < 3149824) { s = we;  d = web; off = i - 3145728; }
    else if (i < 3153920) { s = wsp; d = wsb; off = i - 3149824; }
    else                  { s = whp; d = whb; off = i - 3153920; }
    const float4 v = *(const float4*)(s + off);
    short4v o;
    o[0] = f2bf(v.x); o[1] = f2bf(v.y); o[2] = f2bf(v.z); o[3] = f2bf(v.w);
    *(short4v*)(d + off) = o;
}

// ============================================================================
// K1: qkv = x @ w_qkv^T, M-TILE=128, LDS-staged B (double-buffered) with
// A-prefetch, and LDS-STAGED OUTPUT: the (tm,o0) block's result is a
// contiguous 128x64 tile of qkv -> stage in LDS (pad 68: conflict-free) and
// store as coalesced b128 rows (was: 32 scalar u16 stores/thread, 32B txns).
// ============================================================================
__global__ __launch_bounds__(256) void k1_qkv(const u16* __restrict__ x,
                                              const u16* __restrict__ wqkv,
                                              u16* __restrict__ qkv) {
    __shared__ u16 sB[2][64 * 40];
    __shared__ u16 sOut[128][68];
    const int tm = blockIdx.x * 128;
    const int o0 = blockIdx.y * 64;
    const int tid = threadIdx.x, lane = tid & 63, w = tid >> 6;
    const int l15 = lane & 15, quad = lane >> 4;
    const int arow = tm + w * 16 + l15;
    const int brow = tid >> 2, bj = (tid & 3) * 8;
    const int bOff = brow * 40 + bj;
    const u16* bsrc = wqkv + (size_t)(o0 + brow) * CC + bj;

    floatx4 acc[2][4];
    #pragma unroll
    for (int qt = 0; qt < 2; ++qt)
        #pragma unroll
        for (int s = 0; s < 4; ++s) acc[qt][s] = (floatx4){0.f, 0.f, 0.f, 0.f};

    *(short8*)&sB[0][bOff] = *(const short8*)bsrc;
    short8 a0c = *(const short8*)(x + (size_t)arow * CC + quad * 8);
    short8 a1c = *(const short8*)(x + (size_t)(arow + 64) * CC + quad * 8);
    __syncthreads();

    #pragma unroll 1
    for (int kc = 0; kc < CC / 32; ++kc) {
        const int cur = kc & 1, nxt = cur ^ 1;
        const bool more = (kc + 1 < CC / 32);
        short8 pB, pa0, pa1;
        if (more) {
            pB  = *(const short8*)(bsrc + (kc + 1) * 32);
            pa0 = *(const short8*)(x + (size_t)arow * CC + (kc + 1) * 32 + quad * 8);
            pa1 = *(const short8*)(x + (size_t)(arow + 64) * CC + (kc + 1) * 32 + quad * 8);
        }
        #pragma unroll
        for (int s = 0; s < 4; ++s) {
            short8 b = *(const short8*)&sB[cur][(s * 16 + l15) * 40 + quad * 8];
            acc[0][s] = mfma16(a0c, b, acc[0][s]);
            acc[1][s] = mfma16(a1c, b, acc[1][s]);
        }
        if (more) {
            *(short8*)&sB[nxt][bOff] = pB;
            a0c = pa0; a1c = pa1;
        }
        __syncthreads();
    }
    // stage C-layout results into the 128x64 output tile
    #pragma unroll
    for (int qt = 0; qt < 2; ++qt)
        #pragma unroll
        for (int s = 0; s < 4; ++s)
            #pragma unroll
            for (int r = 0; r < 4; ++r)
                sOut[qt * 64 + w * 16 + quad * 4 + r][s * 16 + l15] =
                    (u16)f2bf(acc[qt][s][r]);
    __syncthreads();
    // coalesced store: whole tile is qkv[sq_i][b][h][tm..tm+127][0..63]
    {
        const int sq_i = o0 >> 9, h = (o0 & 511) >> 6, b = tm >> 10;
        u16* base = qkv + ((((size_t)sq_i * BB + b) * HH + h) * NN + (tm & 1023)) * 64;
        const int row = tid >> 1, col0 = (tid & 1) * 32;
        u16* dp = base + (size_t)row * 64 + col0;
        #pragma unroll
        for (int j = 0; j < 4; ++j)
            *(short8*)(dp + j * 8) = *(const short8*)&sOut[row][col0 + j * 8];
    }
}

// ============================================================================
// K2: per-token embeddings + norms + V transpose (hoisted global loads).
// ============================================================================
__global__ __launch_bounds__(256) void k2_embed(
    const u16* __restrict__ qkv,
    const u16* __restrict__ we, const float* __restrict__ be,
    const u16* __restrict__ wsp, const float* __restrict__ bsp,
    const u16* __restrict__ whp, const float* __restrict__ bhp,
    u16* __restrict__ eq, u16* __restrict__ ek,
    u16* __restrict__ sq, u16* __restrict__ sk,
    u16* __restrict__ hq, u16* __restrict__ hk,
    float* __restrict__ eqn, float* __restrict__ ekn,
    float* __restrict__ hqn, float* __restrict__ hkn,
    u16* __restrict__ vt) {
    const int bh = blockIdx.x, n0 = blockIdx.y * 64;
    const int b = bh >> 3, h = bh & 7;
    const int tid = threadIdx.x, lane = tid & 63, w = tid >> 6;
    const int l15 = lane & 15, quad = lane >> 4;

    __shared__ u16 stgE[64][72];
    __shared__ u16 stgS[64][72];
    __shared__ u16 stgH[64][40];
    const int srow = tid >> 2;
    const int scol = (tid & 3) * 16;
    const int hcol = (tid & 3) * 8;

    short8 afr2[2][2];
    const int tokA = n0 + w * 16 + l15;
    #pragma unroll
    for (int src = 0; src < 2; ++src) {
        const u16* qbase = qkv + (((size_t)src * BB + b) * HH + h) * NN * 64;
        #pragma unroll
        for (int c = 0; c < 2; ++c)
            afr2[src][c] = *(const short8*)(qbase + (size_t)tokA * 64 + c * 32 + quad * 8);
    }
    short8 vband0, vband1;
    {
        const u16* vbase = qkv + (((size_t)2 * BB + b) * HH + h) * NN * 64;
        const u16* p = vbase + (size_t)(n0 + srow) * 64 + scol;
        vband0 = *(const short8*)p;
        vband1 = *(const short8*)(p + 8);
    }

    for (int src = 0; src < 2; ++src) {
        floatx4 ce[4], cs[4], ch[2];
        #pragma unroll
        for (int i = 0; i < 4; ++i) { ce[i] = (floatx4){0.f,0.f,0.f,0.f}; cs[i] = (floatx4){0.f,0.f,0.f,0.f}; }
        #pragma unroll
        for (int i = 0; i < 2; ++i) ch[i] = (floatx4){0.f,0.f,0.f,0.f};

        #pragma unroll
        for (int c = 0; c < 2; ++c) {
            const int k0 = c * 32 + quad * 8;
            #pragma unroll
            for (int i = 0; i < 4; ++i) {
                short8 bf = *(const short8*)(we + (size_t)(i * 16 + l15) * 64 + k0);
                ce[i] = mfma16(afr2[src][c], bf, ce[i]);
            }
            #pragma unroll
            for (int i = 0; i < 4; ++i) {
                short8 bf = *(const short8*)(wsp + (size_t)(i * 16 + l15) * 64 + k0);
                cs[i] = mfma16(afr2[src][c], bf, cs[i]);
            }
            #pragma unroll
            for (int i = 0; i < 2; ++i) {
                short8 bf = *(const short8*)(whp + (size_t)(i * 16 + l15) * 64 + k0);
                ch[i] = mfma16(afr2[src][c], bf, ch[i]);
            }
        }
        u16* edst = src ? ek : eq;
        u16* sdst = src ? sk : sq;
        u16* hdst = src ? hk : hq;
        float* endst = src ? ekn : eqn;
        float* hndst = src ? hkn : hqn;
        const int myrow = w * 16 + quad * 4;

        float epart[4] = {0.f, 0.f, 0.f, 0.f};
        #pragma unroll
        for (int i = 0; i < 4; ++i) {
            const float bias = be[i * 16 + l15];
            #pragma unroll
            for (int r = 0; r < 4; ++r) {
                const float v = ce[i][r] + bias;
                const short vb = f2bf(v);
                const float vr = __uint_as_float(((unsigned)(u16)vb) << 16);
                epart[r] += vr * vr;
                stgE[myrow + r][i * 16 + l15] = (u16)vb;
            }
        }
        #pragma unroll
        for (int r = 0; r < 4; ++r) {
            const float s = qsum16(epart[r]);
            if (l15 == 0) endst[(size_t)bh * NN + n0 + myrow + r] = s;
        }
        float sv[4][4], sn2[4] = {0.f, 0.f, 0.f, 0.f};
        #pragma unroll
        for (int i = 0; i < 4; ++i) {
            const float bias = bsp[i * 16 + l15];
            #pragma unroll
            for (int r = 0; r < 4; ++r) {
                const float v = cs[i][r] + bias;
                sv[i][r] = v;
                sn2[r] += v * v;
            }
        }
        float inv[4];
        #pragma unroll
        for (int r = 0; r < 4; ++r) {
            const float t = qsum16(sn2[r]);
            inv[r] = FRCP(fmaxf(FSQRT(t), 1e-12f));
        }
        #pragma unroll
        for (int i = 0; i < 4; ++i) {
            #pragma unroll
            for (int r = 0; r < 4; ++r)
                stgS[myrow + r][i * 16 + l15] = (u16)f2bf(sv[i][r] * inv[r]);
        }
        float hpart[4] = {0.f, 0.f, 0.f, 0.f};
        #pragma unroll
        for (int i = 0; i < 2; ++i) {
            const float bias = bhp[i * 16 + l15];
            #pragma unroll
            for (int r = 0; r < 4; ++r) {
                const float v = ftanh(ch[i][r] + bias);
                const short vb = f2bf(v);
                const float vr = __uint_as_float(((unsigned)(u16)vb) << 16);
                hpart[r] += vr * vr;
                stgH[myrow + r][i * 16 + l15] = (u16)vb;
            }
        }
        #pragma unroll
        for (int r = 0; r < 4; ++r) {
            const float s = qsum16(hpart[r]);
            if (l15 == 0) hndst[(size_t)bh * NN + n0 + myrow + r] = s;
        }
        __syncthreads();
        {
            u16* dpE = edst + ((size_t)bh * NN + n0 + srow) * 64 + scol;
            *(short8*)dpE = *(const short8*)&stgE[srow][scol];
            *(short8*)(dpE + 8) = *(const short8*)&stgE[srow][scol + 8];
            u16* dpS = sdst + ((size_t)bh * NN + n0 + srow) * 64 + scol;
            *(short8*)dpS = *(const short8*)&stgS[srow][scol];
            *(short8*)(dpS + 8) = *(const short8*)&stgS[srow][scol + 8];
            u16* dpH = hdst + ((size_t)bh * NN + n0 + srow) * 32 + hcol;
            *(short8*)dpH = *(const short8*)&stgH[srow][hcol];
        }
        __syncthreads();
    }

    *(short8*)(&stgE[srow][scol]) = vband0;
    *(short8*)(&stgE[srow][scol + 8]) = vband1;
    __syncthreads();
    {
        const int d = tid >> 2, nn0 = (tid & 3) * 16;
        short8 o1, o2;
        #pragma unroll
        for (int j = 0; j < 8; ++j) o1[j] = (short)stgE[nn0 + j][d];
        #pragma unroll
        for (int j = 0; j < 8; ++j) o2[j] = (short)stgE[nn0 + 8 + j][d];
        u16* dst = vt + ((size_t)bh * 64 + d) * NN + n0 + nn0;
        *(short8*)dst = o1;
        *(short8*)(dst + 8) = o2;
    }
}

// ============================================================================
// K3: fused distance-attention, q-TILE=128, double-buffered staging,
// packed-fp32 per-entry math (unchanged from R13).
// ============================================================================
__global__ __launch_bounds__(256, 2) void k3_attn(
    const u16* __restrict__ eq, const u16* __restrict__ ek,
    const u16* __restrict__ sq, const u16* __restrict__ sk,
    const u16* __restrict__ hq, const u16* __restrict__ hk,
    const float* __restrict__ eqn, const float* __restrict__ ekn,
    const float* __restrict__ hqn, const float* __restrict__ hkn,
    const u16* __restrict__ vt,
    float* __restrict__ opart, float* __restrict__ lpart,
    const float* __restrict__ pA, const float* __restrict__ pB,
    const float* __restrict__ pG, const float* __restrict__ pT) {
    __shared__ u16 sE[2][32 * 72];
    __shared__ u16 sS[2][32 * 72];
    __shared__ u16 sH[2][32 * 40];
    __shared__ u16 sV[2][64 * 40];
    __shared__ float sEN[2][32];
    __shared__ float sHN[2][32];
    __shared__ u16 plds[4][2][16][36];

    const int bh = blockIdx.x, q0b = blockIdx.y * 128, split = blockIdx.z;
    const int tid = threadIdx.x, lane = tid & 63, w = tid >> 6;
    const int l15 = lane & 15, quad = lane >> 4;
    const int q0 = q0b + w * 16;

    const float invT = 1.0f / softplusf(pT[0]);
    const float L2E = 1.4426950408889634f;
    const float kE = -softplusf(pA[0]) * invT * L2E;
    const float kS = -softplusf(pB[0]) * invT * L2E;
    const float kH2 = -softplusf(pG[0]) * invT;

    const f2 kEv = {kE, kE}, kSv = {kS, kS}, kHv = {kH2, kH2};
    const f2 m2v = {-2.f, -2.f}, e12v = {1e-12f, 1e-12f};
    const f2 c99v = {0.999999f, 0.999999f};
    const f2 one2 = {1.f, 1.f}, zero2 = {0.f, 0.f};
    const f2 oneps2 = {1.f + 1e-6f, 1.f + 1e-6f}, negone2 = {-1.f, -1.f};
    const f2 pa3v = {-0.0187293f, -0.0187293f}, pa2v = {0.0742610f, 0.0742610f};
    const f2 pa1v = {-0.2121144f, -0.2121144f}, pa0v = {1.5707288f, 1.5707288f};
    const float PI_F = 3.14159265358979f;

    const u16* ekb = ek + (size_t)bh * NN * 64;
    const u16* skb = sk + (size_t)bh * NN * 64;
    const u16* hkb = hk + (size_t)bh * NN * 32;
    const u16* vtb = vt + (size_t)bh * 64 * NN;
    const float* eknb = ekn + (size_t)bh * NN;
    const float* hknb = hkn + (size_t)bh * NN;

    const int kt0 = split * (NN / 32 / NSPLIT);
    const int ktend = kt0 + NN / 32 / NSPLIT;
    const int mbase = kt0 * 32;

    const int eKey = tid >> 3, eJ = (tid & 7) * 8;
    const int hKey = tid >> 2, hJ = (tid & 3) * 8;
    const int vD   = tid >> 2, vJ = (tid & 3) * 8;
    const int eOff = eKey * 72 + eJ;
    const int hOff = hKey * 40 + hJ;
    const int vOff = vD * 40 + vJ;

    short8 Ea[2][2], Sa[2][2], Ha[2];
    #pragma unroll
    for (int qt = 0; qt < 2; ++qt) {
        const size_t qrow = (size_t)bh * NN + q0 + qt * 64 + l15;
        #pragma unroll
        for (int c = 0; c < 2; ++c) {
            Ea[qt][c] = *(const short8*)(eq + qrow * 64 + c * 32 + quad * 8);
            Sa[qt][c] = *(const short8*)(sq + qrow * 64 + c * 32 + quad * 8);
        }
        Ha[qt] = *(const short8*)(hq + qrow * 32 + quad * 8);
    }

    f2 eqp[2][2], hqp[2][2], icq[2][2];
    #pragma unroll
    for (int qt = 0; qt < 2; ++qt) {
        #pragma unroll
        for (int p = 0; p < 2; ++p) {
            const int t0 = q0 + qt * 64 + quad * 4 + 2 * p;
            const float e0 = eqn[(size_t)bh * NN + t0], e1 = eqn[(size_t)bh * NN + t0 + 1];
            const float h0 = hqn[(size_t)bh * NN + t0], h1 = hqn[(size_t)bh * NN + t0 + 1];
            eqp[qt][p] = (f2){e0, e1};
            hqp[qt][p] = (f2){h0, h1};
            icq[qt][p] = (f2){FRCP(1.0f - h0), FRCP(1.0f - h1)};
        }
    }

    {
        short8 vE = *(const short8*)(ekb + (size_t)(mbase + eKey) * 64 + eJ);
        short8 vS = *(const short8*)(skb + (size_t)(mbase + eKey) * 64 + eJ);
        short8 vV = *(const short8*)(vtb + (size_t)vD * NN + mbase + vJ);
        *(short8*)&sE[0][eOff] = vE;
        *(short8*)&sS[0][eOff] = vS;
        *(short8*)&sV[0][vOff] = vV;
        if (tid < 128) {
            short8 vH = *(const short8*)(hkb + (size_t)(mbase + hKey) * 32 + hJ);
            *(short8*)&sH[0][hOff] = vH;
        } else if (tid < 136) {
            float4 vN = *(const float4*)(eknb + mbase + (tid - 128) * 4);
            *(float4*)&sEN[0][(tid - 128) * 4] = vN;
        } else if (tid < 144) {
            float4 vN = *(const float4*)(hknb + mbase + (tid - 136) * 4);
            *(float4*)&sHN[0][(tid - 136) * 4] = vN;
        }
        __syncthreads();
    }

    floatx4 oacc[2][4];
    #pragma unroll
    for (int qt = 0; qt < 2; ++qt)
        #pragma unroll
        for (int db = 0; db < 4; ++db) oacc[qt][db] = (floatx4){0.f, 0.f, 0.f, 0.f};
    f2 lsum2[2][2] = {{{0.f, 0.f}, {0.f, 0.f}}, {{0.f, 0.f}, {0.f, 0.f}}};

    #pragma unroll 1
    for (int kt = kt0; kt < ktend; ++kt) {
        const int cur = (kt - kt0) & 1, nxt = cur ^ 1;
        const bool more = (kt + 1 < ktend);

        short8 pE, pS, pV, pH;
        float4 pEN, pHN;
        if (more) {
            const int m0 = (kt + 1) * 32;
            pE = *(const short8*)(ekb + (size_t)(m0 + eKey) * 64 + eJ);
            pS = *(const short8*)(skb + (size_t)(m0 + eKey) * 64 + eJ);
            pV = *(const short8*)(vtb + (size_t)vD * NN + m0 + vJ);
            if (tid < 128) {
                pH = *(const short8*)(hkb + (size_t)(m0 + hKey) * 32 + hJ);
            } else if (tid < 136) {
                pEN = *(const float4*)(eknb + m0 + (tid - 128) * 4);
            } else if (tid < 144) {
                pHN = *(const float4*)(hknb + m0 + (tid - 136) * 4);
            }
        }

        #pragma unroll
        for (int sub = 0; sub < 2; ++sub) {
            const int row = sub * 16 + l15;
            short8 Eb0 = *(const short8*)&sE[cur][row * 72 + quad * 8];
            short8 Eb1 = *(const short8*)&sE[cur][row * 72 + 32 + quad * 8];
            short8 Sb0 = *(const short8*)&sS[cur][row * 72 + quad * 8];
            short8 Sb1 = *(const short8*)&sS[cur][row * 72 + 32 + quad * 8];
            short8 Hb  = *(const short8*)&sH[cur][row * 40 + quad * 8];

            const float ekn_m = sEN[cur][row];
            const float hkn_m = sHN[cur][row];
            const float rck = FRCP(1.0f - hkn_m);
            const f2 rckv = {rck + rck, rck + rck};
            const f2 ekn2 = {ekn_m, ekn_m};
            const f2 hkn2 = {hkn_m, hkn_m};

            #pragma unroll
            for (int qt = 0; qt < 2; ++qt) {
                floatx4 z = (floatx4){0.f, 0.f, 0.f, 0.f};
                floatx4 se = mfma16(Ea[qt][1], Eb1, mfma16(Ea[qt][0], Eb0, z));
                floatx4 ss = mfma16(Sa[qt][1], Sb1, mfma16(Sa[qt][0], Sb0, z));
                floatx4 sh = mfma16(Ha[qt], Hb, z);

                #pragma unroll
                for (int p = 0; p < 2; ++p) {
                    f2 se2 = {se[2 * p], se[2 * p + 1]};
                    f2 ss2 = {ss[2 * p], ss[2 * p + 1]};
                    f2 sh2 = {sh[2 * p], sh[2 * p + 1]};
                    f2 d1 = EMAX(EFMA(se2, m2v, eqp[qt][p] + ekn2), e12v);
                    f2 dE2 = {FSQRT(d1.x), FSQRT(d1.y)};
                    f2 t2 = EMIN(EABS(ss2), c99v);
                    f2 pol = EFMA(EFMA(EFMA(pa3v, t2, pa2v), t2, pa1v), t2, pa0v);
                    f2 om = one2 - t2;
                    f2 sq2 = {FSQRT(om.x), FSQRT(om.y)};
                    f2 rr2 = sq2 * pol;
                    f2 dS2;
                    dS2.x = (ss2.x >= 0.f) ? rr2.x : PI_F - rr2.x;
                    dS2.y = (ss2.y >= 0.f) ? rr2.y : PI_F - rr2.y;
                    f2 dns2 = EMAX(EFMA(sh2, m2v, hqp[qt][p] + hkn2), zero2);
                    f2 arg2 = EMAX(EFMA(dns2 * icq[qt][p], rckv, one2), oneps2);
                    f2 qa = EFMA(arg2, arg2, negone2);
                    f2 sq3 = {FSQRT(qa.x), FSQRT(qa.y)};
                    f2 xs2 = arg2 + sq3;
                    f2 lgH2 = {FLOG2(xs2.x), FLOG2(xs2.y)};
                    f2 lg2v = EFMA(dE2, kEv, EFMA(dS2, kSv, lgH2 * kHv));
                    const float p0 = FEXP2(lg2v.x);
                    const float p1 = FEXP2(lg2v.y);
                    const unsigned u0 = __float_as_uint(p0);
                    const unsigned u1 = __float_as_uint(p1);
                    f2 tr = {__uint_as_float(u0 & 0xffff0000u),
                             __uint_as_float(u1 & 0xffff0000u)};
                    lsum2[qt][p] += tr;
                    plds[w][qt][quad * 4 + 2 * p][sub * 16 + l15] = (u16)(u0 >> 16);
                    plds[w][qt][quad * 4 + 2 * p + 1][sub * 16 + l15] = (u16)(u1 >> 16);
                }
            }
        }
        short8 Vb[4];
        #pragma unroll
        for (int db = 0; db < 4; ++db)
            Vb[db] = *(const short8*)&sV[cur][(db * 16 + l15) * 40 + quad * 8];
        #pragma unroll
        for (int qt = 0; qt < 2; ++qt) {
            short8 Pa = *(const short8*)(&plds[w][qt][l15][quad * 8]);
            #pragma unroll
            for (int db = 0; db < 4; ++db)
                oacc[qt][db] = mfma16(Pa, Vb[db], oacc[qt][db]);
        }

        if (more) {
            *(short8*)&sE[nxt][eOff] = pE;
            *(short8*)&sS[nxt][eOff] = pS;
            *(short8*)&sV[nxt][vOff] = pV;
            if (tid < 128) {
                *(short8*)&sH[nxt][hOff] = pH;
            } else if (tid < 136) {
                *(float4*)&sEN[nxt][(tid - 128) * 4] = pEN;
            } else if (tid < 144) {
                *(float4*)&sHN[nxt][(tid - 136) * 4] = pHN;
            }
        }
        __syncthreads();
    }

    float* obase = opart + ((size_t)split * BHCNT + bh) * NN * 64;
    #pragma unroll
    for (int qt = 0; qt < 2; ++qt) {
        #pragma unroll
        for (int db = 0; db < 4; ++db) {
            #pragma unroll
            for (int r = 0; r < 4; ++r) {
                const int t = q0 + qt * 64 + quad * 4 + r;
                obase[(size_t)t * 64 + db * 16 + l15] = oacc[qt][db][r];
            }
        }
        #pragma unroll
        for (int r = 0; r < 4; ++r) {
            const float lv = (r & 1) ? lsum2[qt][r >> 1].y : lsum2[qt][r >> 1].x;
            const float s = qsum16(lv);
            if (l15 == 0)
                lpart[((size_t)split * BHCNT + bh) * NN + q0 + qt * 64 + quad * 4 + r] = s;
        }
    }
}

// ============================================================================
// K3R: combine NSPLIT partials -> ao bf16 [B][N][512]. 4 d's per thread.
// ============================================================================
__global__ __launch_bounds__(256) void k3r_reduce(
    const float* __restrict__ opart, const float* __restrict__ lpart,
    u16* __restrict__ ao) {
    const size_t gid = (size_t)blockIdx.x * 256 + threadIdx.x;
    const size_t base = gid * 4;
    const int token = (int)(base >> 6);
    const int d0 = (int)(base & 63);
    float4 acc = {0.f, 0.f, 0.f, 0.f};
    float ls = 0.f;
    #pragma unroll
    for (int s = 0; s < NSPLIT; ++s) {
        const float4 v = *(const float4*)(opart + ((size_t)s * BHCNT * NN + token) * 64 + d0);
        acc.x += v.x; acc.y += v.y; acc.z += v.z; acc.w += v.w;
        ls += lpart[(size_t)s * BHCNT * NN + token];
    }
    const float inv = FRCP(ls);
    const int bh = token >> 10, n = token & (NN - 1);
    const int b = bh >> 3, h = bh & 7;
    short4v o;
    o[0] = f2bf(acc.x * inv); o[1] = f2bf(acc.y * inv);
    o[2] = f2bf(acc.z * inv); o[3] = f2bf(acc.w * inv);
    *(short4v*)(ao + ((size_t)b * NN + n) * INNERD + h * 64 + d0) = o;
}

// ============================================================================
// K4: out = ao @ w_proj^T + b_proj, M-TILE=128, A-prefetch, and LDS-STAGED
// OUTPUT in two 64-row phases (64x66 fp32 tile, bias folded at staging;
// store phase = 4 coalesced float4 per thread).
// ============================================================================
__global__ __launch_bounds__(256) void k4_proj(const u16* __restrict__ ao,
                                               const u16* __restrict__ wp,
                                               const float* __restrict__ bp,
                                               float* __restrict__ out) {
    __shared__ u16 sB[2][64 * 40];
    __shared__ float sOutF[64][66];
    const int tm = blockIdx.x * 128;
    const int o0 = blockIdx.y * 64;
    const int tid = threadIdx.x, lane = tid & 63, w = tid >> 6;
    const int l15 = lane & 15, quad = lane >> 4;
    const int arow = tm + w * 16 + l15;
    const int brow = tid >> 2, bj = (tid & 3) * 8;
    const int bOff = brow * 40 + bj;
    const u16* bsrc = wp + (size_t)(o0 + brow) * INNERD + bj;

    floatx4 acc[2][4];
    #pragma unroll
    for (int qt = 0; qt < 2; ++qt)
        #pragma unroll
        for (int s = 0; s < 4; ++s) acc[qt][s] = (floatx4){0.f, 0.f, 0.f, 0.f};

    *(short8*)&sB[0][bOff] = *(const short8*)bsrc;
    short8 a0c = *(const short8*)(ao + (size_t)arow * INNERD + quad * 8);
    short8 a1c = *(const short8*)(ao + (size_t)(arow + 64) * INNERD + quad * 8);
    __syncthreads();

    #pragma unroll 1
    for (int kc = 0; kc < INNERD / 32; ++kc) {
        const int cur = kc & 1, nxt = cur ^ 1;
        const bool more = (kc + 1 < INNERD / 32);
        short8 pB, pa0, pa1;
        if (more) {
            pB  = *(const short8*)(bsrc + (kc + 1) * 32);
            pa0 = *(const short8*)(ao + (size_t)arow * INNERD + (kc + 1) * 32 + quad * 8);
            pa1 = *(const short8*)(ao + (size_t)(arow + 64) * INNERD + (kc + 1) * 32 + quad * 8);
        }
        #pragma unroll
        for (int s = 0; s < 4; ++s) {
            short8 b = *(const short8*)&sB[cur][(s * 16 + l15) * 40 + quad * 8];
            acc[0][s] = mfma16(a0c, b, acc[0][s]);
            acc[1][s] = mfma16(a1c, b, acc[1][s]);
        }
        if (more) {
            *(short8*)&sB[nxt][bOff] = pB;
            a0c = pa0; a1c = pa1;
        }
        __syncthreads();
    }
    // two-phase LDS-staged output (bias folded at staging)
    const int orow = tid >> 2, ocol0 = (tid & 3) * 16;
    #pragma unroll 1
    for (int qt = 0; qt < 2; ++qt) {
        #pragma unroll
        for (int s = 0; s < 4; ++s) {
            const float bias = bp[o0 + s * 16 + l15];
            #pragma unroll
            for (int r = 0; r < 4; ++r)
                sOutF[w * 16 + quad * 4 + r][s * 16 + l15] = acc[qt][s][r] + bias;
        }
        __syncthreads();
        {
            float* dp = out + (size_t)(tm + qt * 64 + orow) * CC + o0 + ocol0;
            #pragma unroll
            for (int j = 0; j < 4; ++j)
                *(float4*)(dp + j * 4) = *(const float4*)&sOutF[orow][ocol0 + j * 4];
        }
        __syncthreads();
    }
}

extern "C" void kernel_launch(void* const* d_in, const int* in_sizes, int n_in,
                              void* d_out, int out_size, void* d_ws, size_t ws_size,
                              hipStream_t stream) {
    const float* x     = (const float*)d_in[0];
    const float* wqkv  = (const float*)d_in[1];
    const float* wproj = (const float*)d_in[2];
    const float* bproj = (const float*)d_in[3];
    const float* we    = (const float*)d_in[4];
    const float* be    = (const float*)d_in[5];
    const float* wsp   = (const float*)d_in[6];
    const float* bsp   = (const float*)d_in[7];
    const float* whp   = (const float*)d_in[8];
    const float* bhp   = (const float*)d_in[9];
    const float* pA    = (const float*)d_in[10];
    const float* pB    = (const float*)d_in[11];
    const float* pG    = (const float*)d_in[12];
    const float* pT    = (const float*)d_in[13];

    char* ws = (char*)d_ws;
    u16* xb  = (u16*)(ws + OFF_XB);
    u16* wqb = (u16*)(ws + OFF_WQB);
    u16* wpb = (u16*)(ws + OFF_WPB);
    u16* web = (u16*)(ws + OFF_WEB);
    u16* wsb = (u16*)(ws + OFF_WSB);
    u16* whb = (u16*)(ws + OFF_WHB);
    u16* qkv = (u16*)(ws + OFF_QKV);
    u16* eq = (u16*)(ws + OFF_EQ);
    u16* ek = (u16*)(ws + OFF_EK);
    u16* sq = (u16*)(ws + OFF_SQ);
    u16* sk = (u16*)(ws + OFF_SK);
    u16* hq = (u16*)(ws + OFF_HQ);
    u16* hk = (u16*)(ws + OFF_HK);
    u16* vt = (u16*)(ws + OFF_VT);
    float* eqn = (float*)(ws + OFF_EQN);
    float* ekn = (float*)(ws + OFF_EKN);
    float* hqn = (float*)(ws + OFF_HQN);
    float* hkn = (float*)(ws + OFF_HKN);
    u16* ao = (u16*)(ws + OFF_AO);
    float* opart = (float*)(ws + OFF_OP);
    float* lpart = (float*)(ws + OFF_LP);

    k0_cvt<<<3082, 256, 0, stream>>>(x, wqkv, wproj, we, wsp, whp,
                                     xb, wqb, wpb, web, wsb, whb);
    k1_qkv<<<dim3(MTOK / 128, 1536 / 64), 256, 0, stream>>>(xb, wqb, qkv);
    k2_embed<<<dim3(BHCNT, NN / 64), 256, 0, stream>>>(
        qkv, web, be, wsb, bsp, whb, bhp,
        eq, ek, sq, sk, hq, hk, eqn, ekn, hqn, hkn, vt);
    k3_attn<<<dim3(BHCNT, NN / 128, NSPLIT), 256, 0, stream>>>(
        eq, ek, sq, sk, hq, hk, eqn, ekn, hqn, hkn, vt, opart, lpart,
        pA, pB, pG, pT);
    k3r_reduce<<<(BHCNT * NN * 64 / 4) / 256, 256, 0, stream>>>(opart, lpart, ao);
    k4_proj<<<dim3(MTOK / 128, CC / 64), 256, 0, stream>>>(ao, wpb, bproj, (float*)d_out);
}

// Round 15
// 189.584 us; speedup vs baseline: 1.0739x; 1.0739x over previous
//
#include <hip/hip_runtime.h>
#include <math.h>

typedef unsigned short u16;
typedef __attribute__((ext_vector_type(8))) short short8;
typedef __attribute__((ext_vector_type(4))) short short4v;
typedef __attribute__((ext_vector_type(4))) float floatx4;
typedef __attribute__((ext_vector_type(2))) float f2;

#define BB 4
#define NN 1024
#define CC 512
#define HH 8
#define INNERD 512
#define BHCNT 32
#define MTOK 4096
#define NSPLIT 2

// ---- workspace layout (bytes) ----
constexpr size_t OFF_XB  = 0;                          // bf16 [4096][512]   = 4194304
constexpr size_t OFF_WQB = 4194304;                    // bf16 [1536][512]   = 1572864
constexpr size_t OFF_WPB = 5767168;                    // bf16 [512][512]    = 524288
constexpr size_t OFF_WEB = 6291456;                    // bf16 [64][64]      = 8192
constexpr size_t OFF_WSB = 6299648;                    // bf16 [64][64]      = 8192
constexpr size_t OFF_WHB = 6307840;                    // bf16 [32][64]      = 4096
constexpr size_t OFF_QKV = 6311936;                    // bf16 [3][B][H][N][64] = 12582912
constexpr size_t OFF_EQ  = 18894848;                   // bf16 [BH][N][64]   = 4194304
constexpr size_t OFF_EK  = 23089152;
constexpr size_t OFF_SQ  = 27283456;
constexpr size_t OFF_SK  = 31477760;
constexpr size_t OFF_HQ  = 35672064;                   // bf16 [BH][N][32]   = 2097152
constexpr size_t OFF_HK  = 37769216;
constexpr size_t OFF_VT  = 39866368;                   // bf16 [BH][64][N]   = 4194304
constexpr size_t OFF_EQN = 44060672;                   // fp32 [BH][N]       = 131072
constexpr size_t OFF_EKN = 44191744;
constexpr size_t OFF_HQN = 44322816;
constexpr size_t OFF_HKN = 44453888;
constexpr size_t OFF_AO  = 44584960;                   // bf16 [B][N][512]   = 4194304
constexpr size_t OFF_OP  = 48779264;                   // fp32 [2][BH][N][64]= 16777216
constexpr size_t OFF_LP  = 65556480;                   // fp32 [2][BH][N]    = 262144

// ---- fast native transcendentals (compile-safe fallbacks) ----
#if __has_builtin(__builtin_amdgcn_exp2f)
#define FEXP2(x) __builtin_amdgcn_exp2f(x)
#else
#define FEXP2(x) exp2f(x)
#endif
#if __has_builtin(__builtin_amdgcn_logf)
#define FLOG2(x) __builtin_amdgcn_logf(x)
#else
#define FLOG2(x) log2f(x)
#endif
#if __has_builtin(__builtin_amdgcn_sqrtf)
#define FSQRT(x) __builtin_amdgcn_sqrtf(x)
#else
#define FSQRT(x) sqrtf(x)
#endif
#if __has_builtin(__builtin_amdgcn_rcpf)
#define FRCP(x) __builtin_amdgcn_rcpf(x)
#else
#define FRCP(x) (1.0f / (x))
#endif

#define EFMA(a,b,c) __builtin_elementwise_fma(a,b,c)
#define EMAX(a,b)   __builtin_elementwise_max(a,b)
#define EMIN(a,b)   __builtin_elementwise_min(a,b)
#define EABS(a)     __builtin_elementwise_abs(a)

__device__ __forceinline__ short f2bf(float f) {
    unsigned u = __float_as_uint(f);
    unsigned r = u + 0x7fffu + ((u >> 16) & 1u);
    return (short)(r >> 16);
}
__device__ __forceinline__ floatx4 mfma16(short8 a, short8 b, floatx4 c) {
    return __builtin_amdgcn_mfma_f32_16x16x32_bf16(a, b, c, 0, 0, 0);
}
__device__ __forceinline__ float softplusf(float x) { return log1pf(expf(x)); }
__device__ __forceinline__ float qsum16(float v) {
    v += __shfl_xor(v, 1); v += __shfl_xor(v, 2);
    v += __shfl_xor(v, 4); v += __shfl_xor(v, 8);
    return v;
}
// fast tanh: (t-1)/(t+1), t = exp2(2x*log2e). bf16-rounded after.
__device__ __forceinline__ float ftanh(float x) {
    const float t = FEXP2(x * 2.8853900817779268f);
    return (t - 1.0f) * FRCP(t + 1.0f);
}

// ============================================================================
// K0: fp32 -> bf16 conversion of x / w_qkv / w_proj / w_e / w_s / w_h.
// ============================================================================
__global__ __launch_bounds__(256) void k0_cvt(
    const float* __restrict__ x, const float* __restrict__ wq,
    const float* __restrict__ wp, const float* __restrict__ we,
    const float* __restrict__ wsp, const float* __restrict__ whp,
    u16* __restrict__ xb, u16* __restrict__ wqb, u16* __restrict__ wpb,
    u16* __restrict__ web, u16* __restrict__ wsb, u16* __restrict__ whb) {
    const size_t i = ((size_t)blockIdx.x * 256 + threadIdx.x) * 4;
    const float* s; u16* d; size_t off;
    if (i < 2097152)      { s = x;   d = xb;  off = i; }
    else if (i < 2883584) { s = wq;  d = wqb; off = i - 2097152; }
    else if (i < 3145728) { s = wp;  d = wpb; off = i - 2883584; }
    else if (i < 3149824) { s = we;  d = web; off = i - 3145728; }
    else if (i < 3153920) { s = wsp; d = wsb; off = i - 3149824; }
    else                  { s = whp; d = whb; off = i - 3153920; }
    const float4 v = *(const float4*)(s + off);
    short4v o;
    o[0] = f2bf(v.x); o[1] = f2bf(v.y); o[2] = f2bf(v.z); o[3] = f2bf(v.w);
    *(short4v*)(d + off) = o;
}

// ============================================================================
// K1: qkv = x @ w_qkv^T, M-TILE=128, LDS-staged B (double-buffered),
// A-prefetch across the barrier. (R13 form; R14's LDS-staged epilogue
// regressed via occupancy loss -- reverted.)
// ============================================================================
__global__ __launch_bounds__(256) void k1_qkv(const u16* __restrict__ x,
                                              const u16* __restrict__ wqkv,
                                              u16* __restrict__ qkv) {
    __shared__ u16 sB[2][64 * 40];
    const int tm = blockIdx.x * 128;
    const int o0 = blockIdx.y * 64;
    const int tid = threadIdx.x, lane = tid & 63, w = tid >> 6;
    const int l15 = lane & 15, quad = lane >> 4;
    const int arow = tm + w * 16 + l15;
    const int brow = tid >> 2, bj = (tid & 3) * 8;
    const int bOff = brow * 40 + bj;
    const u16* bsrc = wqkv + (size_t)(o0 + brow) * CC + bj;

    floatx4 acc[2][4];
    #pragma unroll
    for (int qt = 0; qt < 2; ++qt)
        #pragma unroll
        for (int s = 0; s < 4; ++s) acc[qt][s] = (floatx4){0.f, 0.f, 0.f, 0.f};

    *(short8*)&sB[0][bOff] = *(const short8*)bsrc;
    short8 a0c = *(const short8*)(x + (size_t)arow * CC + quad * 8);
    short8 a1c = *(const short8*)(x + (size_t)(arow + 64) * CC + quad * 8);
    __syncthreads();

    #pragma unroll 1
    for (int kc = 0; kc < CC / 32; ++kc) {
        const int cur = kc & 1, nxt = cur ^ 1;
        const bool more = (kc + 1 < CC / 32);
        short8 pB, pa0, pa1;
        if (more) {
            pB  = *(const short8*)(bsrc + (kc + 1) * 32);
            pa0 = *(const short8*)(x + (size_t)arow * CC + (kc + 1) * 32 + quad * 8);
            pa1 = *(const short8*)(x + (size_t)(arow + 64) * CC + (kc + 1) * 32 + quad * 8);
        }
        #pragma unroll
        for (int s = 0; s < 4; ++s) {
            short8 b = *(const short8*)&sB[cur][(s * 16 + l15) * 40 + quad * 8];
            acc[0][s] = mfma16(a0c, b, acc[0][s]);
            acc[1][s] = mfma16(a1c, b, acc[1][s]);
        }
        if (more) {
            *(short8*)&sB[nxt][bOff] = pB;
            a0c = pa0; a1c = pa1;
        }
        __syncthreads();
    }
    #pragma unroll
    for (int qt = 0; qt < 2; ++qt) {
        #pragma unroll
        for (int s = 0; s < 4; ++s) {
            const int o = o0 + s * 16 + l15;
            const int sq_i = o >> 9, rem = o & 511;
            const int h = rem >> 6, d = rem & 63;
            #pragma unroll
            for (int r = 0; r < 4; ++r) {
                const int tok = tm + qt * 64 + w * 16 + quad * 4 + r;
                const int bb = tok >> 10, n = tok & (NN - 1);
                qkv[((((size_t)sq_i * BB + bb) * HH + h) * NN + n) * 64 + d] =
                    (u16)f2bf(acc[qt][s][r]);
            }
        }
    }
}

// ============================================================================
// K2: per-token embeddings + norms + V transpose. SPLIT BY SRC across
// blockIdx.z (q-side / k-side): per-thread serial chain halves, block count
// doubles (512->1024 = 4 blocks/CU) -- k2 is latency-bound on long scalar +
// qsum16 chains. V-transpose runs in the src==1 block.
// ============================================================================
__global__ __launch_bounds__(256) void k2_embed(
    const u16* __restrict__ qkv,
    const u16* __restrict__ we, const float* __restrict__ be,
    const u16* __restrict__ wsp, const float* __restrict__ bsp,
    const u16* __restrict__ whp, const float* __restrict__ bhp,
    u16* __restrict__ eq, u16* __restrict__ ek,
    u16* __restrict__ sq, u16* __restrict__ sk,
    u16* __restrict__ hq, u16* __restrict__ hk,
    float* __restrict__ eqn, float* __restrict__ ekn,
    float* __restrict__ hqn, float* __restrict__ hkn,
    u16* __restrict__ vt) {
    const int bh = blockIdx.x, n0 = blockIdx.y * 64;
    const int src = blockIdx.z;
    const int b = bh >> 3, h = bh & 7;
    const int tid = threadIdx.x, lane = tid & 63, w = tid >> 6;
    const int l15 = lane & 15, quad = lane >> 4;

    __shared__ u16 stgE[64][72];
    __shared__ u16 stgS[64][72];
    __shared__ u16 stgH[64][40];
    const int srow = tid >> 2;
    const int scol = (tid & 3) * 16;
    const int hcol = (tid & 3) * 8;

    // hoisted global loads for this src
    short8 afr[2];
    const int tokA = n0 + w * 16 + l15;
    {
        const u16* qbase = qkv + (((size_t)src * BB + b) * HH + h) * NN * 64;
        #pragma unroll
        for (int c = 0; c < 2; ++c)
            afr[c] = *(const short8*)(qbase + (size_t)tokA * 64 + c * 32 + quad * 8);
    }
    short8 vband0, vband1;
    if (src == 1) {
        const u16* vbase = qkv + (((size_t)2 * BB + b) * HH + h) * NN * 64;
        const u16* p = vbase + (size_t)(n0 + srow) * 64 + scol;
        vband0 = *(const short8*)p;
        vband1 = *(const short8*)(p + 8);
    }

    floatx4 ce[4], cs[4], ch[2];
    #pragma unroll
    for (int i = 0; i < 4; ++i) { ce[i] = (floatx4){0.f,0.f,0.f,0.f}; cs[i] = (floatx4){0.f,0.f,0.f,0.f}; }
    #pragma unroll
    for (int i = 0; i < 2; ++i) ch[i] = (floatx4){0.f,0.f,0.f,0.f};

    #pragma unroll
    for (int c = 0; c < 2; ++c) {
        const int k0 = c * 32 + quad * 8;
        #pragma unroll
        for (int i = 0; i < 4; ++i) {
            short8 bf = *(const short8*)(we + (size_t)(i * 16 + l15) * 64 + k0);
            ce[i] = mfma16(afr[c], bf, ce[i]);
        }
        #pragma unroll
        for (int i = 0; i < 4; ++i) {
            short8 bf = *(const short8*)(wsp + (size_t)(i * 16 + l15) * 64 + k0);
            cs[i] = mfma16(afr[c], bf, cs[i]);
        }
        #pragma unroll
        for (int i = 0; i < 2; ++i) {
            short8 bf = *(const short8*)(whp + (size_t)(i * 16 + l15) * 64 + k0);
            ch[i] = mfma16(afr[c], bf, ch[i]);
        }
    }
    u16* edst = src ? ek : eq;
    u16* sdst = src ? sk : sq;
    u16* hdst = src ? hk : hq;
    float* endst = src ? ekn : eqn;
    float* hndst = src ? hkn : hqn;
    const int myrow = w * 16 + quad * 4;

    float epart[4] = {0.f, 0.f, 0.f, 0.f};
    #pragma unroll
    for (int i = 0; i < 4; ++i) {
        const float bias = be[i * 16 + l15];
        #pragma unroll
        for (int r = 0; r < 4; ++r) {
            const float v = ce[i][r] + bias;
            const short vb = f2bf(v);
            const float vr = __uint_as_float(((unsigned)(u16)vb) << 16);
            epart[r] += vr * vr;
            stgE[myrow + r][i * 16 + l15] = (u16)vb;
        }
    }
    #pragma unroll
    for (int r = 0; r < 4; ++r) {
        const float s = qsum16(epart[r]);
        if (l15 == 0) endst[(size_t)bh * NN + n0 + myrow + r] = s;
    }
    float sv[4][4], sn2[4] = {0.f, 0.f, 0.f, 0.f};
    #pragma unroll
    for (int i = 0; i < 4; ++i) {
        const float bias = bsp[i * 16 + l15];
        #pragma unroll
        for (int r = 0; r < 4; ++r) {
            const float v = cs[i][r] + bias;
            sv[i][r] = v;
            sn2[r] += v * v;
        }
    }
    float inv[4];
    #pragma unroll
    for (int r = 0; r < 4; ++r) {
        const float t = qsum16(sn2[r]);
        inv[r] = FRCP(fmaxf(FSQRT(t), 1e-12f));
    }
    #pragma unroll
    for (int i = 0; i < 4; ++i) {
        #pragma unroll
        for (int r = 0; r < 4; ++r)
            stgS[myrow + r][i * 16 + l15] = (u16)f2bf(sv[i][r] * inv[r]);
    }
    float hpart[4] = {0.f, 0.f, 0.f, 0.f};
    #pragma unroll
    for (int i = 0; i < 2; ++i) {
        const float bias = bhp[i * 16 + l15];
        #pragma unroll
        for (int r = 0; r < 4; ++r) {
            const float v = ftanh(ch[i][r] + bias);
            const short vb = f2bf(v);
            const float vr = __uint_as_float(((unsigned)(u16)vb) << 16);
            hpart[r] += vr * vr;
            stgH[myrow + r][i * 16 + l15] = (u16)vb;
        }
    }
    #pragma unroll
    for (int r = 0; r < 4; ++r) {
        const float s = qsum16(hpart[r]);
        if (l15 == 0) hndst[(size_t)bh * NN + n0 + myrow + r] = s;
    }
    __syncthreads();
    {
        u16* dpE = edst + ((size_t)bh * NN + n0 + srow) * 64 + scol;
        *(short8*)dpE = *(const short8*)&stgE[srow][scol];
        *(short8*)(dpE + 8) = *(const short8*)&stgE[srow][scol + 8];
        u16* dpS = sdst + ((size_t)bh * NN + n0 + srow) * 64 + scol;
        *(short8*)dpS = *(const short8*)&stgS[srow][scol];
        *(short8*)(dpS + 8) = *(const short8*)&stgS[srow][scol + 8];
        u16* dpH = hdst + ((size_t)bh * NN + n0 + srow) * 32 + hcol;
        *(short8*)dpH = *(const short8*)&stgH[srow][hcol];
    }

    if (src == 1) {
        __syncthreads();
        *(short8*)(&stgE[srow][scol]) = vband0;
        *(short8*)(&stgE[srow][scol + 8]) = vband1;
        __syncthreads();
        const int d = tid >> 2, nn0 = (tid & 3) * 16;
        short8 o1, o2;
        #pragma unroll
        for (int j = 0; j < 8; ++j) o1[j] = (short)stgE[nn0 + j][d];
        #pragma unroll
        for (int j = 0; j < 8; ++j) o2[j] = (short)stgE[nn0 + 8 + j][d];
        u16* dst = vt + ((size_t)bh * 64 + d) * NN + n0 + nn0;
        *(short8*)dst = o1;
        *(short8*)(dst + 8) = o2;
    }
}

// ============================================================================
// K3: fused distance-attention, q-TILE=128, double-buffered staging,
// packed-fp32 per-entry math (unchanged from R13).
// ============================================================================
__global__ __launch_bounds__(256, 2) void k3_attn(
    const u16* __restrict__ eq, const u16* __restrict__ ek,
    const u16* __restrict__ sq, const u16* __restrict__ sk,
    const u16* __restrict__ hq, const u16* __restrict__ hk,
    const float* __restrict__ eqn, const float* __restrict__ ekn,
    const float* __restrict__ hqn, const float* __restrict__ hkn,
    const u16* __restrict__ vt,
    float* __restrict__ opart, float* __restrict__ lpart,
    const float* __restrict__ pA, const float* __restrict__ pB,
    const float* __restrict__ pG, const float* __restrict__ pT) {
    __shared__ u16 sE[2][32 * 72];
    __shared__ u16 sS[2][32 * 72];
    __shared__ u16 sH[2][32 * 40];
    __shared__ u16 sV[2][64 * 40];
    __shared__ float sEN[2][32];
    __shared__ float sHN[2][32];
    __shared__ u16 plds[4][2][16][36];

    const int bh = blockIdx.x, q0b = blockIdx.y * 128, split = blockIdx.z;
    const int tid = threadIdx.x, lane = tid & 63, w = tid >> 6;
    const int l15 = lane & 15, quad = lane >> 4;
    const int q0 = q0b + w * 16;

    const float invT = 1.0f / softplusf(pT[0]);
    const float L2E = 1.4426950408889634f;
    const float kE = -softplusf(pA[0]) * invT * L2E;
    const float kS = -softplusf(pB[0]) * invT * L2E;
    const float kH2 = -softplusf(pG[0]) * invT;

    const f2 kEv = {kE, kE}, kSv = {kS, kS}, kHv = {kH2, kH2};
    const f2 m2v = {-2.f, -2.f}, e12v = {1e-12f, 1e-12f};
    const f2 c99v = {0.999999f, 0.999999f};
    const f2 one2 = {1.f, 1.f}, zero2 = {0.f, 0.f};
    const f2 oneps2 = {1.f + 1e-6f, 1.f + 1e-6f}, negone2 = {-1.f, -1.f};
    const f2 pa3v = {-0.0187293f, -0.0187293f}, pa2v = {0.0742610f, 0.0742610f};
    const f2 pa1v = {-0.2121144f, -0.2121144f}, pa0v = {1.5707288f, 1.5707288f};
    const float PI_F = 3.14159265358979f;

    const u16* ekb = ek + (size_t)bh * NN * 64;
    const u16* skb = sk + (size_t)bh * NN * 64;
    const u16* hkb = hk + (size_t)bh * NN * 32;
    const u16* vtb = vt + (size_t)bh * 64 * NN;
    const float* eknb = ekn + (size_t)bh * NN;
    const float* hknb = hkn + (size_t)bh * NN;

    const int kt0 = split * (NN / 32 / NSPLIT);
    const int ktend = kt0 + NN / 32 / NSPLIT;
    const int mbase = kt0 * 32;

    const int eKey = tid >> 3, eJ = (tid & 7) * 8;
    const int hKey = tid >> 2, hJ = (tid & 3) * 8;
    const int vD   = tid >> 2, vJ = (tid & 3) * 8;
    const int eOff = eKey * 72 + eJ;
    const int hOff = hKey * 40 + hJ;
    const int vOff = vD * 40 + vJ;

    short8 Ea[2][2], Sa[2][2], Ha[2];
    #pragma unroll
    for (int qt = 0; qt < 2; ++qt) {
        const size_t qrow = (size_t)bh * NN + q0 + qt * 64 + l15;
        #pragma unroll
        for (int c = 0; c < 2; ++c) {
            Ea[qt][c] = *(const short8*)(eq + qrow * 64 + c * 32 + quad * 8);
            Sa[qt][c] = *(const short8*)(sq + qrow * 64 + c * 32 + quad * 8);
        }
        Ha[qt] = *(const short8*)(hq + qrow * 32 + quad * 8);
    }

    f2 eqp[2][2], hqp[2][2], icq[2][2];
    #pragma unroll
    for (int qt = 0; qt < 2; ++qt) {
        #pragma unroll
        for (int p = 0; p < 2; ++p) {
            const int t0 = q0 + qt * 64 + quad * 4 + 2 * p;
            const float e0 = eqn[(size_t)bh * NN + t0], e1 = eqn[(size_t)bh * NN + t0 + 1];
            const float h0 = hqn[(size_t)bh * NN + t0], h1 = hqn[(size_t)bh * NN + t0 + 1];
            eqp[qt][p] = (f2){e0, e1};
            hqp[qt][p] = (f2){h0, h1};
            icq[qt][p] = (f2){FRCP(1.0f - h0), FRCP(1.0f - h1)};
        }
    }

    {
        short8 vE = *(const short8*)(ekb + (size_t)(mbase + eKey) * 64 + eJ);
        short8 vS = *(const short8*)(skb + (size_t)(mbase + eKey) * 64 + eJ);
        short8 vV = *(const short8*)(vtb + (size_t)vD * NN + mbase + vJ);
        *(short8*)&sE[0][eOff] = vE;
        *(short8*)&sS[0][eOff] = vS;
        *(short8*)&sV[0][vOff] = vV;
        if (tid < 128) {
            short8 vH = *(const short8*)(hkb + (size_t)(mbase + hKey) * 32 + hJ);
            *(short8*)&sH[0][hOff] = vH;
        } else if (tid < 136) {
            float4 vN = *(const float4*)(eknb + mbase + (tid - 128) * 4);
            *(float4*)&sEN[0][(tid - 128) * 4] = vN;
        } else if (tid < 144) {
            float4 vN = *(const float4*)(hknb + mbase + (tid - 136) * 4);
            *(float4*)&sHN[0][(tid - 136) * 4] = vN;
        }
        __syncthreads();
    }

    floatx4 oacc[2][4];
    #pragma unroll
    for (int qt = 0; qt < 2; ++qt)
        #pragma unroll
        for (int db = 0; db < 4; ++db) oacc[qt][db] = (floatx4){0.f, 0.f, 0.f, 0.f};
    f2 lsum2[2][2] = {{{0.f, 0.f}, {0.f, 0.f}}, {{0.f, 0.f}, {0.f, 0.f}}};

    #pragma unroll 1
    for (int kt = kt0; kt < ktend; ++kt) {
        const int cur = (kt - kt0) & 1, nxt = cur ^ 1;
        const bool more = (kt + 1 < ktend);

        short8 pE, pS, pV, pH;
        float4 pEN, pHN;
        if (more) {
            const int m0 = (kt + 1) * 32;
            pE = *(const short8*)(ekb + (size_t)(m0 + eKey) * 64 + eJ);
            pS = *(const short8*)(skb + (size_t)(m0 + eKey) * 64 + eJ);
            pV = *(const short8*)(vtb + (size_t)vD * NN + m0 + vJ);
            if (tid < 128) {
                pH = *(const short8*)(hkb + (size_t)(m0 + hKey) * 32 + hJ);
            } else if (tid < 136) {
                pEN = *(const float4*)(eknb + m0 + (tid - 128) * 4);
            } else if (tid < 144) {
                pHN = *(const float4*)(hknb + m0 + (tid - 136) * 4);
            }
        }

        #pragma unroll
        for (int sub = 0; sub < 2; ++sub) {
            const int row = sub * 16 + l15;
            short8 Eb0 = *(const short8*)&sE[cur][row * 72 + quad * 8];
            short8 Eb1 = *(const short8*)&sE[cur][row * 72 + 32 + quad * 8];
            short8 Sb0 = *(const short8*)&sS[cur][row * 72 + quad * 8];
            short8 Sb1 = *(const short8*)&sS[cur][row * 72 + 32 + quad * 8];
            short8 Hb  = *(const short8*)&sH[cur][row * 40 + quad * 8];

            const float ekn_m = sEN[cur][row];
            const float hkn_m = sHN[cur][row];
            const float rck = FRCP(1.0f - hkn_m);
            const f2 rckv = {rck + rck, rck + rck};
            const f2 ekn2 = {ekn_m, ekn_m};
            const f2 hkn2 = {hkn_m, hkn_m};

            #pragma unroll
            for (int qt = 0; qt < 2; ++qt) {
                floatx4 z = (floatx4){0.f, 0.f, 0.f, 0.f};
                floatx4 se = mfma16(Ea[qt][1], Eb1, mfma16(Ea[qt][0], Eb0, z));
                floatx4 ss = mfma16(Sa[qt][1], Sb1, mfma16(Sa[qt][0], Sb0, z));
                floatx4 sh = mfma16(Ha[qt], Hb, z);

                #pragma unroll
                for (int p = 0; p < 2; ++p) {
                    f2 se2 = {se[2 * p], se[2 * p + 1]};
                    f2 ss2 = {ss[2 * p], ss[2 * p + 1]};
                    f2 sh2 = {sh[2 * p], sh[2 * p + 1]};
                    f2 d1 = EMAX(EFMA(se2, m2v, eqp[qt][p] + ekn2), e12v);
                    f2 dE2 = {FSQRT(d1.x), FSQRT(d1.y)};
                    f2 t2 = EMIN(EABS(ss2), c99v);
                    f2 pol = EFMA(EFMA(EFMA(pa3v, t2, pa2v), t2, pa1v), t2, pa0v);
                    f2 om = one2 - t2;
                    f2 sq2 = {FSQRT(om.x), FSQRT(om.y)};
                    f2 rr2 = sq2 * pol;
                    f2 dS2;
                    dS2.x = (ss2.x >= 0.f) ? rr2.x : PI_F - rr2.x;
                    dS2.y = (ss2.y >= 0.f) ? rr2.y : PI_F - rr2.y;
                    f2 dns2 = EMAX(EFMA(sh2, m2v, hqp[qt][p] + hkn2), zero2);
                    f2 arg2 = EMAX(EFMA(dns2 * icq[qt][p], rckv, one2), oneps2);
                    f2 qa = EFMA(arg2, arg2, negone2);
                    f2 sq3 = {FSQRT(qa.x), FSQRT(qa.y)};
                    f2 xs2 = arg2 + sq3;
                    f2 lgH2 = {FLOG2(xs2.x), FLOG2(xs2.y)};
                    f2 lg2v = EFMA(dE2, kEv, EFMA(dS2, kSv, lgH2 * kHv));
                    const float p0 = FEXP2(lg2v.x);
                    const float p1 = FEXP2(lg2v.y);
                    const unsigned u0 = __float_as_uint(p0);
                    const unsigned u1 = __float_as_uint(p1);
                    f2 tr = {__uint_as_float(u0 & 0xffff0000u),
                             __uint_as_float(u1 & 0xffff0000u)};
                    lsum2[qt][p] += tr;
                    plds[w][qt][quad * 4 + 2 * p][sub * 16 + l15] = (u16)(u0 >> 16);
                    plds[w][qt][quad * 4 + 2 * p + 1][sub * 16 + l15] = (u16)(u1 >> 16);
                }
            }
        }
        short8 Vb[4];
        #pragma unroll
        for (int db = 0; db < 4; ++db)
            Vb[db] = *(const short8*)&sV[cur][(db * 16 + l15) * 40 + quad * 8];
        #pragma unroll
        for (int qt = 0; qt < 2; ++qt) {
            short8 Pa = *(const short8*)(&plds[w][qt][l15][quad * 8]);
            #pragma unroll
            for (int db = 0; db < 4; ++db)
                oacc[qt][db] = mfma16(Pa, Vb[db], oacc[qt][db]);
        }

        if (more) {
            *(short8*)&sE[nxt][eOff] = pE;
            *(short8*)&sS[nxt][eOff] = pS;
            *(short8*)&sV[nxt][vOff] = pV;
            if (tid < 128) {
                *(short8*)&sH[nxt][hOff] = pH;
            } else if (tid < 136) {
                *(float4*)&sEN[nxt][(tid - 128) * 4] = pEN;
            } else if (tid < 144) {
                *(float4*)&sHN[nxt][(tid - 136) * 4] = pHN;
            }
        }
        __syncthreads();
    }

    float* obase = opart + ((size_t)split * BHCNT + bh) * NN * 64;
    #pragma unroll
    for (int qt = 0; qt < 2; ++qt) {
        #pragma unroll
        for (int db = 0; db < 4; ++db) {
            #pragma unroll
            for (int r = 0; r < 4; ++r) {
                const int t = q0 + qt * 64 + quad * 4 + r;
                obase[(size_t)t * 64 + db * 16 + l15] = oacc[qt][db][r];
            }
        }
        #pragma unroll
        for (int r = 0; r < 4; ++r) {
            const float lv = (r & 1) ? lsum2[qt][r >> 1].y : lsum2[qt][r >> 1].x;
            const float s = qsum16(lv);
            if (l15 == 0)
                lpart[((size_t)split * BHCNT + bh) * NN + q0 + qt * 64 + quad * 4 + r] = s;
        }
    }
}

// ============================================================================
// K3R: combine NSPLIT partials -> ao bf16 [B][N][512]. 4 d's per thread.
// ============================================================================
__global__ __launch_bounds__(256) void k3r_reduce(
    const float* __restrict__ opart, const float* __restrict__ lpart,
    u16* __restrict__ ao) {
    const size_t gid = (size_t)blockIdx.x * 256 + threadIdx.x;
    const size_t base = gid * 4;
    const int token = (int)(base >> 6);
    const int d0 = (int)(base & 63);
    float4 acc = {0.f, 0.f, 0.f, 0.f};
    float ls = 0.f;
    #pragma unroll
    for (int s = 0; s < NSPLIT; ++s) {
        const float4 v = *(const float4*)(opart + ((size_t)s * BHCNT * NN + token) * 64 + d0);
        acc.x += v.x; acc.y += v.y; acc.z += v.z; acc.w += v.w;
        ls += lpart[(size_t)s * BHCNT * NN + token];
    }
    const float inv = FRCP(ls);
    const int bh = token >> 10, n = token & (NN - 1);
    const int b = bh >> 3, h = bh & 7;
    short4v o;
    o[0] = f2bf(acc.x * inv); o[1] = f2bf(acc.y * inv);
    o[2] = f2bf(acc.z * inv); o[3] = f2bf(acc.w * inv);
    *(short4v*)(ao + ((size_t)b * NN + n) * INNERD + h * 64 + d0) = o;
}

// ============================================================================
// K4: out = ao @ w_proj^T + b_proj, M-TILE=128, A-prefetch (R13 form).
// ============================================================================
__global__ __launch_bounds__(256) void k4_proj(const u16* __restrict__ ao,
                                               const u16* __restrict__ wp,
                                               const float* __restrict__ bp,
                                               float* __restrict__ out) {
    __shared__ u16 sB[2][64 * 40];
    const int tm = blockIdx.x * 128;
    const int o0 = blockIdx.y * 64;
    const int tid = threadIdx.x, lane = tid & 63, w = tid >> 6;
    const int l15 = lane & 15, quad = lane >> 4;
    const int arow = tm + w * 16 + l15;
    const int brow = tid >> 2, bj = (tid & 3) * 8;
    const int bOff = brow * 40 + bj;
    const u16* bsrc = wp + (size_t)(o0 + brow) * INNERD + bj;

    floatx4 acc[2][4];
    #pragma unroll
    for (int qt = 0; qt < 2; ++qt)
        #pragma unroll
        for (int s = 0; s < 4; ++s) acc[qt][s] = (floatx4){0.f, 0.f, 0.f, 0.f};

    *(short8*)&sB[0][bOff] = *(const short8*)bsrc;
    short8 a0c = *(const short8*)(ao + (size_t)arow * INNERD + quad * 8);
    short8 a1c = *(const short8*)(ao + (size_t)(arow + 64) * INNERD + quad * 8);
    __syncthreads();

    #pragma unroll 1
    for (int kc = 0; kc < INNERD / 32; ++kc) {
        const int cur = kc & 1, nxt = cur ^ 1;
        const bool more = (kc + 1 < INNERD / 32);
        short8 pB, pa0, pa1;
        if (more) {
            pB  = *(const short8*)(bsrc + (kc + 1) * 32);
            pa0 = *(const short8*)(ao + (size_t)arow * INNERD + (kc + 1) * 32 + quad * 8);
            pa1 = *(const short8*)(ao + (size_t)(arow + 64) * INNERD + (kc + 1) * 32 + quad * 8);
        }
        #pragma unroll
        for (int s = 0; s < 4; ++s) {
            short8 b = *(const short8*)&sB[cur][(s * 16 + l15) * 40 + quad * 8];
            acc[0][s] = mfma16(a0c, b, acc[0][s]);
            acc[1][s] = mfma16(a1c, b, acc[1][s]);
        }
        if (more) {
            *(short8*)&sB[nxt][bOff] = pB;
            a0c = pa0; a1c = pa1;
        }
        __syncthreads();
    }
    #pragma unroll
    for (int qt = 0; qt < 2; ++qt) {
        #pragma unroll
        for (int s = 0; s < 4; ++s) {
            const int o = o0 + s * 16 + l15;
            const float bias = bp[o];
            #pragma unroll
            for (int r = 0; r < 4; ++r) {
                const int tok = tm + qt * 64 + w * 16 + quad * 4 + r;
                out[(size_t)tok * CC + o] = acc[qt][s][r] + bias;
            }
        }
    }
}

extern "C" void kernel_launch(void* const* d_in, const int* in_sizes, int n_in,
                              void* d_out, int out_size, void* d_ws, size_t ws_size,
                              hipStream_t stream) {
    const float* x     = (const float*)d_in[0];
    const float* wqkv  = (const float*)d_in[1];
    const float* wproj = (const float*)d_in[2];
    const float* bproj = (const float*)d_in[3];
    const float* we    = (const float*)d_in[4];
    const float* be    = (const float*)d_in[5];
    const float* wsp   = (const float*)d_in[6];
    const float* bsp   = (const float*)d_in[7];
    const float* whp   = (const float*)d_in[8];
    const float* bhp   = (const float*)d_in[9];
    const float* pA    = (const float*)d_in[10];
    const float* pB    = (const float*)d_in[11];
    const float* pG    = (const float*)d_in[12];
    const float* pT    = (const float*)d_in[13];

    char* ws = (char*)d_ws;
    u16* xb  = (u16*)(ws + OFF_XB);
    u16* wqb = (u16*)(ws + OFF_WQB);
    u16* wpb = (u16*)(ws + OFF_WPB);
    u16* web = (u16*)(ws + OFF_WEB);
    u16* wsb = (u16*)(ws + OFF_WSB);
    u16* whb = (u16*)(ws + OFF_WHB);
    u16* qkv = (u16*)(ws + OFF_QKV);
    u16* eq = (u16*)(ws + OFF_EQ);
    u16* ek = (u16*)(ws + OFF_EK);
    u16* sq = (u16*)(ws + OFF_SQ);
    u16* sk = (u16*)(ws + OFF_SK);
    u16* hq = (u16*)(ws + OFF_HQ);
    u16* hk = (u16*)(ws + OFF_HK);
    u16* vt = (u16*)(ws + OFF_VT);
    float* eqn = (float*)(ws + OFF_EQN);
    float* ekn = (float*)(ws + OFF_EKN);
    float* hqn = (float*)(ws + OFF_HQN);
    float* hkn = (float*)(ws + OFF_HKN);
    u16* ao = (u16*)(ws + OFF_AO);
    float* opart = (float*)(ws + OFF_OP);
    float* lpart = (float*)(ws + OFF_LP);

    k0_cvt<<<3082, 256, 0, stream>>>(x, wqkv, wproj, we, wsp, whp,
                                     xb, wqb, wpb, web, wsb, whb);
    k1_qkv<<<dim3(MTOK / 128, 1536 / 64), 256, 0, stream>>>(xb, wqb, qkv);
    k2_embed<<<dim3(BHCNT, NN / 64, 2), 256, 0, stream>>>(
        qkv, web, be, wsb, bsp, whb, bhp,
        eq, ek, sq, sk, hq, hk, eqn, ekn, hqn, hkn, vt);
    k3_attn<<<dim3(BHCNT, NN / 128, NSPLIT), 256, 0, stream>>>(
        eq, ek, sq, sk, hq, hk, eqn, ekn, hqn, hkn, vt, opart, lpart,
        pA, pB, pG, pT);
    k3r_reduce<<<(BHCNT * NN * 64 / 4) / 256, 256, 0, stream>>>(opart, lpart, ao);
    k4_proj<<<dim3(MTOK / 128, CC / 64), 256, 0, stream>>>(ao, wpb, bproj, (float*)d_out);
}